// Round 2
// baseline (935.859 us; speedup 1.0000x reference)
//
#include <hip/hip_runtime.h>
#include <stdint.h>

#define E_  64
#define T_  128
#define D_  1024
#define H_  1024
#define N1_ 2048   // 2*HID

typedef __attribute__((ext_vector_type(8))) short bf16x8;
typedef __attribute__((ext_vector_type(4))) float f32x4;

// pack two f32 -> two bf16 (round-to-nearest) in one v_perm
__device__ inline uint32_t pack_bf16(float lo, float hi) {
  union { float f; uint32_t u; } a, b;
  a.f = lo; b.f = hi;
  return __builtin_amdgcn_perm(b.u + 0x8000u, a.u + 0x8000u, 0x07060302u);
}
__device__ inline uint16_t f2bf(float f) {
  union { float f; uint32_t u; } v; v.f = f;
  return (uint16_t)((v.u + 0x8000u) >> 16);
}

// LDS layout: sm[q][row][8] bf16, q = k>>3 (4 slabs of 8 k), slab padded to
// 1032 el (2064 B = 129*16 -> +4 bank rotation per slab). b128 read at
// (row, q) hits bank-quad (row+q)%8 -> uniform 8 lanes/quad = optimal.
#define SLAB 1032
__device__ inline int lds_off(int row, int q) { return q * SLAB + row * 8; }

// ---------------- Kernel 1: H = X @ W1 + b1 ; Act = swiglu(H) (bf16) ----------------
__global__ __launch_bounds__(256, 3) void k1_gemm_swiglu(
    const float* __restrict__ X, const float* __restrict__ W1,
    const float* __restrict__ B1, uint16_t* __restrict__ Act) {
  int blk = blockIdx.x;                     // 1024 blocks
  int e  = (blk & 7) + ((blk >> 7) << 3);   // same-expert blocks share blk%8 (XCD)
  int nt = (blk >> 3) & 15;                 // 16 column tiles of 128 over N1=2048

  __shared__ uint16_t Asm[4 * SLAB];
  __shared__ uint16_t Bsm[4 * SLAB];

  int tid  = threadIdx.x;
  int lane = tid & 63;
  int w    = tid >> 6;
  int wm   = (w & 1) << 6;
  int wn   = (w >> 1) << 6;

  f32x4 acc[4][4];
  #pragma unroll
  for (int i = 0; i < 4; ++i)
    #pragma unroll
    for (int j = 0; j < 4; ++j) { f32x4 z = {0.f,0.f,0.f,0.f}; acc[i][j] = z; }

  const float* Xe  = X  + (size_t)e * T_ * D_;
  const float* W1e = W1 + (size_t)e * D_ * N1_ + nt * 128;

  // A staging: thread owns row a_m, 16 contiguous k at 16*a_qh
  int a_m  = tid & 127;
  int a_qh = tid >> 7;          // 0/1
  // B staging: thread owns cols {2c, 2c+1}, 8 contiguous k-rows at 8*b_q
  int b_c = tid & 63;
  int b_q = tid >> 6;           // 0..3

  float4 aR[4];
  float2 bR[8];
  auto load_tiles = [&](int kb) {
    #pragma unroll
    for (int c = 0; c < 4; ++c)
      aR[c] = *(const float4*)(Xe + (size_t)a_m * D_ + kb + 16 * a_qh + 4 * c);
    #pragma unroll
    for (int r = 0; r < 8; ++r)
      bR[r] = *(const float2*)(W1e + (size_t)(kb + 8 * b_q + r) * N1_ + 2 * b_c);
  };

  load_tiles(0);
  #pragma unroll 1
  for (int kt = 0; kt < D_ / 32; ++kt) {
    __syncthreads();
    // A: two b128 writes (k-chunks 2*a_qh, 2*a_qh+1)
    {
      uint4 w0 = make_uint4(pack_bf16(aR[0].x, aR[0].y), pack_bf16(aR[0].z, aR[0].w),
                            pack_bf16(aR[1].x, aR[1].y), pack_bf16(aR[1].z, aR[1].w));
      uint4 w1 = make_uint4(pack_bf16(aR[2].x, aR[2].y), pack_bf16(aR[2].z, aR[2].w),
                            pack_bf16(aR[3].x, aR[3].y), pack_bf16(aR[3].z, aR[3].w));
      *(uint4*)&Asm[lds_off(a_m, 2 * a_qh)]     = w0;
      *(uint4*)&Asm[lds_off(a_m, 2 * a_qh + 1)] = w1;
    }
    // B: col 2c -> row' c ; col 2c+1 -> row' c+64 (permuted storage)
    {
      uint4 w0 = make_uint4(pack_bf16(bR[0].x, bR[1].x), pack_bf16(bR[2].x, bR[3].x),
                            pack_bf16(bR[4].x, bR[5].x), pack_bf16(bR[6].x, bR[7].x));
      uint4 w1 = make_uint4(pack_bf16(bR[0].y, bR[1].y), pack_bf16(bR[2].y, bR[3].y),
                            pack_bf16(bR[4].y, bR[5].y), pack_bf16(bR[6].y, bR[7].y));
      *(uint4*)&Bsm[lds_off(b_c,      b_q)] = w0;
      *(uint4*)&Bsm[lds_off(b_c + 64, b_q)] = w1;
    }
    if (kt < D_ / 32 - 1) load_tiles((kt + 1) * 32);  // prefetch overlaps MFMA
    __syncthreads();

    bf16x8 af[4], bf[4];
    int q = lane >> 4;
    #pragma unroll
    for (int i = 0; i < 4; ++i)
      af[i] = *(const bf16x8*)&Asm[lds_off(wm + i * 16 + (lane & 15), q)];
    #pragma unroll
    for (int j = 0; j < 4; ++j) {
      int n = wn + j * 16 + (lane & 15);
      int rp = (n >> 1) + ((n & 1) << 6);
      bf[j] = *(const bf16x8*)&Bsm[lds_off(rp, q)];
    }
    #pragma unroll
    for (int i = 0; i < 4; ++i)
      #pragma unroll
      for (int j = 0; j < 4; ++j)
        acc[i][j] = __builtin_amdgcn_mfma_f32_16x16x32_bf16(af[i], bf[j], acc[i][j], 0, 0, 0);
  }

  // epilogue: bias -> swiglu(pair via shfl_xor 1) -> Act bf16
  uint16_t* Acte = Act + (size_t)e * T_ * H_;
  #pragma unroll
  for (int j = 0; j < 4; ++j) {
    int col = nt * 128 + wn + j * 16 + (lane & 15);
    float bias = B1[e * N1_ + col];
    #pragma unroll
    for (int i = 0; i < 4; ++i) {
      #pragma unroll
      for (int r = 0; r < 4; ++r) {
        float h = acc[i][j][r] + bias;
        float partner = __shfl_xor(h, 1, 64);
        if ((lane & 1) == 0) {
          float xg = fminf(h, 7.0f);
          float xl = fminf(fmaxf(partner, -7.0f), 7.0f);
          float sw = xg / (1.0f + __expf(-1.702f * xg));
          int m = wm + i * 16 + ((lane >> 4) << 2) + r;
          Acte[m * H_ + (col >> 1)] = f2bf(sw * (xl + 1.0f));
        }
      }
    }
  }
}

// ---------------- Kernel 2: OUT = Act @ W2 + b2 (fp32 out) ----------------
__global__ __launch_bounds__(256, 3) void k2_gemm(
    const uint16_t* __restrict__ Act, const float* __restrict__ W2,
    const float* __restrict__ B2, float* __restrict__ OUT) {
  int blk = blockIdx.x;                 // 512 blocks
  int e  = (blk & 7) + ((blk >> 6) << 3);
  int nt = (blk >> 3) & 7;              // 8 column tiles of 128 over D=1024

  __shared__ uint16_t Asm[4 * SLAB];
  __shared__ uint16_t Bsm[4 * SLAB];

  int tid  = threadIdx.x;
  int lane = tid & 63;
  int w    = tid >> 6;
  int wm   = (w & 1) << 6;
  int wn   = (w >> 1) << 6;

  f32x4 acc[4][4];
  #pragma unroll
  for (int i = 0; i < 4; ++i)
    #pragma unroll
    for (int j = 0; j < 4; ++j) { f32x4 z = {0.f,0.f,0.f,0.f}; acc[i][j] = z; }

  const uint16_t* Ae  = Act + (size_t)e * T_ * H_;
  const float*    W2e = W2  + (size_t)e * H_ * D_ + nt * 128;

  int a_m  = tid & 127;
  int a_qh = tid >> 7;          // 0/1 -> k-chunks {2qh, 2qh+1}
  int b_c = tid & 63;
  int b_q = tid >> 6;

  uint4  aU[2];
  float2 bR[8];
  auto load_tiles = [&](int kb) {
    #pragma unroll
    for (int c = 0; c < 2; ++c)
      aU[c] = *(const uint4*)(Ae + (size_t)a_m * H_ + kb + 16 * a_qh + 8 * c);
    #pragma unroll
    for (int r = 0; r < 8; ++r)
      bR[r] = *(const float2*)(W2e + (size_t)(kb + 8 * b_q + r) * D_ + 2 * b_c);
  };

  load_tiles(0);
  #pragma unroll 1
  for (int kt = 0; kt < H_ / 32; ++kt) {
    __syncthreads();
    *(uint4*)&Asm[lds_off(a_m, 2 * a_qh)]     = aU[0];
    *(uint4*)&Asm[lds_off(a_m, 2 * a_qh + 1)] = aU[1];
    {
      uint4 w0 = make_uint4(pack_bf16(bR[0].x, bR[1].x), pack_bf16(bR[2].x, bR[3].x),
                            pack_bf16(bR[4].x, bR[5].x), pack_bf16(bR[6].x, bR[7].x));
      uint4 w1 = make_uint4(pack_bf16(bR[0].y, bR[1].y), pack_bf16(bR[2].y, bR[3].y),
                            pack_bf16(bR[4].y, bR[5].y), pack_bf16(bR[6].y, bR[7].y));
      *(uint4*)&Bsm[lds_off(b_c,      b_q)] = w0;
      *(uint4*)&Bsm[lds_off(b_c + 64, b_q)] = w1;
    }
    if (kt < H_ / 32 - 1) load_tiles((kt + 1) * 32);
    __syncthreads();

    bf16x8 af[4], bf[4];
    int q = lane >> 4;
    #pragma unroll
    for (int i = 0; i < 4; ++i)
      af[i] = *(const bf16x8*)&Asm[lds_off(wm + i * 16 + (lane & 15), q)];
    #pragma unroll
    for (int j = 0; j < 4; ++j) {
      int n = wn + j * 16 + (lane & 15);
      int rp = (n >> 1) + ((n & 1) << 6);
      bf[j] = *(const bf16x8*)&Bsm[lds_off(rp, q)];
    }
    #pragma unroll
    for (int i = 0; i < 4; ++i)
      #pragma unroll
      for (int j = 0; j < 4; ++j)
        acc[i][j] = __builtin_amdgcn_mfma_f32_16x16x32_bf16(af[i], bf[j], acc[i][j], 0, 0, 0);
  }

  float* Oe = OUT + (size_t)e * T_ * D_;
  #pragma unroll
  for (int j = 0; j < 4; ++j) {
    int col = nt * 128 + wn + j * 16 + (lane & 15);
    float bias = B2[e * D_ + col];
    #pragma unroll
    for (int i = 0; i < 4; ++i) {
      #pragma unroll
      for (int r = 0; r < 4; ++r) {
        int m = wm + i * 16 + ((lane >> 4) << 2) + r;
        Oe[(size_t)m * D_ + col] = acc[i][j][r] + bias;
      }
    }
  }
}

extern "C" void kernel_launch(void* const* d_in, const int* in_sizes, int n_in,
                              void* d_out, int out_size, void* d_ws, size_t ws_size,
                              hipStream_t stream) {
  const float* X  = (const float*)d_in[0];
  const float* W1 = (const float*)d_in[1];
  const float* B1 = (const float*)d_in[2];
  const float* W2 = (const float*)d_in[3];
  const float* B2 = (const float*)d_in[4];
  float* OUT = (float*)d_out;
  uint16_t* Act = (uint16_t*)d_ws;  // 64*128*1024 bf16 = 16 MB

  k1_gemm_swiglu<<<dim3(E_ * 16), dim3(256), 0, stream>>>(X, W1, B1, Act);
  k2_gemm<<<dim3(E_ * 8), dim3(256), 0, stream>>>(Act, W2, B2, OUT);
}